// Round 9
// baseline (488.623 us; speedup 1.0000x reference)
//
#include <hip/hip_runtime.h>
#include <hip/hip_bf16.h>

// MSA: x[2,4096,768] f32, wq/wk/wv/wo[768,768] f32, bo[768] f32 -> out f32
// (0) fp32->bf16 convert, (1) fused QKV GEMM (operand-swapped for Q/K ->
// packed b64 epilogue; Q pre-scaled by 0.125*log2e), (2) flash attention
// (64 q-rows/wave, 2-wave blocks, swizzled LDS dbuf K/V, raw v_exp_f32,
// l-sum via ones-column MFMA), (3) out proj (operand-swapped, float4 stores).

#define HEADS 12
#define NSEQ  4096
#define DIM   768
#define DH    64
#define BATCH 2
#define QSCALE 0.18033688f   // (1/8) * log2(e)

typedef __attribute__((ext_vector_type(8))) short bf16x8;
typedef __attribute__((ext_vector_type(4))) float f32x4;
typedef __attribute__((ext_vector_type(4))) short bf16x4;

static __device__ __forceinline__ short f2bf(float f) {
    __hip_bfloat16 h = __float2bfloat16(f);
    return *reinterpret_cast<short*>(&h);
}

// RNE round two fp32 -> packed bf16x2
static __device__ __forceinline__ unsigned pkbf(float a, float b) {
    unsigned ua = __float_as_uint(a), ub = __float_as_uint(b);
    ua += 0x7FFFu + ((ua >> 16) & 1u);
    ub += 0x7FFFu + ((ub >> 16) & 1u);
    return __builtin_amdgcn_perm(ub, ua, 0x07060302);
}

// async global->LDS, 16B per lane
#define GLL(g, l) __builtin_amdgcn_global_load_lds( \
    (const __attribute__((address_space(1))) void*)(g), \
    (__attribute__((address_space(3))) void*)(l), 16, 0, 0)

#define NX (BATCH*NSEQ*DIM)   // 6291456
#define NW (DIM*DIM)          // 589824

// ---------------------------------------------------------------------------
// Kernel 0: fp32 -> bf16 convert.
// ---------------------------------------------------------------------------
__global__ __launch_bounds__(256) void convert_kernel(
    const float* __restrict__ x,  const float* __restrict__ wq,
    const float* __restrict__ wk, const float* __restrict__ wv,
    const float* __restrict__ wo,
    short* __restrict__ xb, short* __restrict__ wqb, short* __restrict__ wkb,
    short* __restrict__ wvb, short* __restrict__ wob)
{
    int i = (blockIdx.x * 256 + threadIdx.x) * 4;
    const float* src; short* dst; int off;
    if      (i < NX)          { src = x;  dst = xb;  off = i; }
    else if (i < NX + NW)     { src = wq; dst = wqb; off = i - NX; }
    else if (i < NX + 2*NW)   { src = wk; dst = wkb; off = i - NX - NW; }
    else if (i < NX + 3*NW)   { src = wv; dst = wvb; off = i - NX - 2*NW; }
    else                      { src = wo; dst = wob; off = i - NX - 3*NW; }
    float4 f = *(const float4*)(src + off);
    bf16x4 o; o[0] = f2bf(f.x); o[1] = f2bf(f.y); o[2] = f2bf(f.z); o[3] = f2bf(f.w);
    *(bf16x4*)(dst + off) = o;
}

// ---------------------------------------------------------------------------
// Kernel 1: fused QKV GEMM. 128x128 block (4 waves, 64x64 quadrants).
// BK=32, GLL staging, dbuf, 1 barrier/step. grid (64, 18).
// which 0/1 (Q,K): operand-SWAPPED mfma(b,a): C row(regs) = dd, col(lane) = n
//   -> 4 consecutive dd per reg quad -> packed b64 stores to [b,h,n,dd].
// which 2 (V): normal orientation, packed b64 stores to Vt[b,h,dd,n].
// ---------------------------------------------------------------------------
__global__ __launch_bounds__(256, 4) void qkv_proj_kernel(
    const short* __restrict__ xb, const short* __restrict__ wqb,
    const short* __restrict__ wkb, const short* __restrict__ wvb,
    short* __restrict__ qb, short* __restrict__ kb, short* __restrict__ vtb)
{
    __shared__ __align__(16) short As[2][128*32];
    __shared__ __align__(16) short Bs[2][128*32];

    const int wave = threadIdx.x >> 6, lane = threadIdx.x & 63;
    const int lr = lane & 15, lq = lane >> 4;
    const int which = blockIdx.y / 6;
    const short* __restrict__ W = (which == 0) ? wqb : ((which == 1) ? wkb : wvb);
    const int m0  = blockIdx.x * 128;
    const int o0l = (blockIdx.y % 6) * 128;

    const short* __restrict__ gA = xb + (size_t)(m0  + wave*32 + (lane>>2)) * DIM + (lane&3)*8;
    const short* __restrict__ gB = W  + (size_t)(o0l + wave*32 + (lane>>2)) * DIM + (lane&3)*8;

    const int wm = (wave & 1) * 64, wn = (wave >> 1) * 64;

    f32x4 acc[4][4];
    #pragma unroll
    for (int i = 0; i < 4; i++)
        #pragma unroll
        for (int j = 0; j < 4; j++) acc[i][j] = (f32x4){0.f, 0.f, 0.f, 0.f};

    GLL(gA,            &As[0][(wave*32     )*32]);
    GLL(gA + 16*DIM,   &As[0][(wave*32 + 16)*32]);
    GLL(gB,            &Bs[0][(wave*32     )*32]);
    GLL(gB + 16*DIM,   &Bs[0][(wave*32 + 16)*32]);
    __syncthreads();

    for (int kt = 0; kt < 24; kt++) {
        const int p = kt & 1;
        if (kt < 23) {
            const int k1 = (kt + 1) * 32;
            GLL(gA + k1,          &As[1-p][(wave*32     )*32]);
            GLL(gA + k1 + 16*DIM, &As[1-p][(wave*32 + 16)*32]);
            GLL(gB + k1,          &Bs[1-p][(wave*32     )*32]);
            GLL(gB + k1 + 16*DIM, &Bs[1-p][(wave*32 + 16)*32]);
        }
        bf16x8 a[4], b[4];
        #pragma unroll
        for (int i = 0; i < 4; i++)
            a[i] = *(const bf16x8*)&As[p][(wm + i*16 + lr)*32 + lq*8];
        #pragma unroll
        for (int j = 0; j < 4; j++)
            b[j] = *(const bf16x8*)&Bs[p][(wn + j*16 + lr)*32 + lq*8];
        if (which == 2) {
            #pragma unroll
            for (int i = 0; i < 4; i++)
                #pragma unroll
                for (int j = 0; j < 4; j++)
                    acc[i][j] = __builtin_amdgcn_mfma_f32_16x16x32_bf16(a[i], b[j], acc[i][j], 0, 0, 0);
        } else {
            #pragma unroll
            for (int i = 0; i < 4; i++)
                #pragma unroll
                for (int j = 0; j < 4; j++)
                    acc[i][j] = __builtin_amdgcn_mfma_f32_16x16x32_bf16(b[j], a[i], acc[i][j], 0, 0, 0);
        }
        __syncthreads();
    }

    if (which == 2) {
        // C[m=n][o=dd]: reg quad r spans 4 consecutive n -> Vt[dd][n] b64
        #pragma unroll
        for (int i = 0; i < 4; i++)
            #pragma unroll
            for (int j = 0; j < 4; j++) {
                const int mb = m0 + wm + i*16 + lq*4;
                const int o  = o0l + wn + j*16 + lr;
                const int bb = mb >> 12, n0 = mb & (NSEQ - 1);
                const int h  = o >> 6,   dd = o & 63;
                bf16x4 v;
                #pragma unroll
                for (int r = 0; r < 4; r++) v[r] = f2bf(acc[i][j][r]);
                *(bf16x4*)(vtb + ((size_t)(bb*HEADS + h) * DH + dd) * NSEQ + n0) = v;
            }
    } else {
        // swapped: C row(reg) = o(dd-dim), col(lane) = m(n-dim)
        short* __restrict__ dst = (which == 0) ? qb : kb;
        const float scale = (which == 0) ? QSCALE : 1.0f;
        #pragma unroll
        for (int i = 0; i < 4; i++)
            #pragma unroll
            for (int j = 0; j < 4; j++) {
                const int m   = m0 + wm + i*16 + lr;          // n (per lane)
                const int ob_ = o0l + wn + j*16 + lq*4;       // dd base (per reg quad)
                const int bb  = m >> 12, n = m & (NSEQ - 1);
                const int h   = ob_ >> 6, dd = ob_ & 63;
                bf16x4 v;
                #pragma unroll
                for (int r = 0; r < 4; r++) v[r] = f2bf(acc[i][j][r] * scale);
                *(bf16x4*)(dst + (((size_t)(bb*HEADS + h) * NSEQ) + n) * DH + dd) = v;
            }
    }
}

// ---------------------------------------------------------------------------
// Kernel 2: flash attention. 768 blocks x 128 threads (2 waves), 64 q/wave.
// Swizzled LDS, dbuf K/V, 1 barrier/tile. S^T = K Q^T; raw v_exp_f32 +
// v_perm pack; PV + ones-column for l.
// ---------------------------------------------------------------------------
__global__ __launch_bounds__(128, 2) void attn_kernel(
    const short* __restrict__ qb, const short* __restrict__ kb,
    const short* __restrict__ vtb, short* __restrict__ ob)
{
    __shared__ __align__(16) short Ks[2][64*64];
    __shared__ __align__(16) short Vs[2][64*64];
    __shared__ __align__(16) short Vones[16*64];
    __shared__ __align__(16) short Ps[2][4][16*64];

    const int wave = threadIdx.x >> 6, lane = threadIdx.x & 63;
    const int lrow = lane & 15, lquad = lane >> 4;

    const int flat = blockIdx.x;
    const int xcd  = flat & 7;
    const int idx  = flat >> 3;
    const int bh   = xcd * 3 + (idx % 3);
    const int qblk = idx / 3;                 // [0,32)
    const int b = bh / HEADS, h = bh % HEADS;
    const int q0 = qblk * 128 + wave * 64;    // 64 q-rows per wave

    const short* __restrict__ Q  = qb  + (size_t)bh * NSEQ * DH;
    const short* __restrict__ K  = kb  + (size_t)bh * NSEQ * DH;
    const short* __restrict__ Vt = vtb + (size_t)bh * DH * NSEQ;

    for (int i = threadIdx.x; i < 16*64; i += 128) Vones[i] = 0x3F80;

    // staging: 128 threads, each loads rows r2+{0,16,32,48}, chunk cc
    const int t  = threadIdx.x;
    const int r2 = t >> 3, cc = t & 7;        // r2 in [0,16)
    const int ccs = (cc ^ (r2 & 7)) * 8;

    bf16x8 aq[4][2];
    #pragma unroll
    for (int rb = 0; rb < 4; rb++)
        #pragma unroll
        for (int kk = 0; kk < 2; kk++)
            aq[rb][kk] = *(const bf16x8*)(Q + (size_t)(q0 + rb*16 + lrow) * DH + kk*32 + lquad*8);

    f32x4 oacc[4][5];
    #pragma unroll
    for (int rb = 0; rb < 4; rb++)
        #pragma unroll
        for (int ct = 0; ct < 5; ct++) oacc[rb][ct] = (f32x4){0.f, 0.f, 0.f, 0.f};

    {   // stage tile 0 into buf 0
        #pragma unroll
        for (int rr = 0; rr < 4; rr++) {
            bf16x8 kv = *(const bf16x8*)(K  + (size_t)(r2 + rr*16) * DH   + cc*8);
            bf16x8 vv = *(const bf16x8*)(Vt + (size_t)(r2 + rr*16) * NSEQ + cc*8);
            *(bf16x8*)&Ks[0][(r2 + rr*16)*64 + ccs] = kv;
            *(bf16x8*)&Vs[0][(r2 + rr*16)*64 + ccs] = vv;
        }
    }
    __syncthreads();

    bf16x8 bv4[2];
    #pragma unroll
    for (int kk = 0; kk < 2; kk++)
        bv4[kk] = *(const bf16x8*)&Vones[lrow*64 + (((kk*4 + lquad) ^ (lrow & 7)) * 8)];

    for (int kt = 0; kt < NSEQ / 64; kt++) {
        const int p = kt & 1;
        bf16x8 kr[4], vr[4];
        if (kt + 1 < NSEQ / 64) {
            const int key1 = (kt + 1) * 64;
            #pragma unroll
            for (int rr = 0; rr < 4; rr++) {
                kr[rr] = *(const bf16x8*)(K  + (size_t)(key1 + r2 + rr*16) * DH   + cc*8);
                vr[rr] = *(const bf16x8*)(Vt + (size_t)(r2 + rr*16) * NSEQ + key1 + cc*8);
            }
        }

        bf16x8 ak[4][2];
        #pragma unroll
        for (int ct = 0; ct < 4; ct++)
            #pragma unroll
            for (int kk = 0; kk < 2; kk++)
                ak[ct][kk] = *(const bf16x8*)&Ks[p][(ct*16 + lrow)*64 + (((kk*4 + lquad) ^ (lrow & 7)) * 8)];

        #pragma unroll
        for (int rb = 0; rb < 4; rb++) {
            f32x4 s[4];
            #pragma unroll
            for (int ct = 0; ct < 4; ct++) s[ct] = (f32x4){0.f, 0.f, 0.f, 0.f};
            #pragma unroll
            for (int kk = 0; kk < 2; kk++)
                #pragma unroll
                for (int ct = 0; ct < 4; ct++)
                    s[ct] = __builtin_amdgcn_mfma_f32_16x16x32_bf16(ak[ct][kk], aq[rb][kk], s[ct], 0, 0, 0);
            #pragma unroll
            for (int ct = 0; ct < 4; ct++) {
                const float e0 = __builtin_amdgcn_exp2f(s[ct][0]);
                const float e1 = __builtin_amdgcn_exp2f(s[ct][1]);
                const float e2 = __builtin_amdgcn_exp2f(s[ct][2]);
                const float e3 = __builtin_amdgcn_exp2f(s[ct][3]);
                const unsigned lo = pkbf(e0, e1), hi = pkbf(e2, e3);
                const int cps = (((ct*2 + (lquad >> 1)) ^ (lrow & 7)) * 8) + (lquad & 1) * 4;
                *(uint2*)&Ps[wave][rb][lrow*64 + cps] = (uint2){lo, hi};
            }
        }

        bf16x8 bv[4][2];
        #pragma unroll
        for (int ct = 0; ct < 4; ct++)
            #pragma unroll
            for (int kk = 0; kk < 2; kk++)
                bv[ct][kk] = *(const bf16x8*)&Vs[p][(ct*16 + lrow)*64 + (((kk*4 + lquad) ^ (lrow & 7)) * 8)];

        #pragma unroll
        for (int rb = 0; rb < 4; rb++) {
            bf16x8 ap[2];
            #pragma unroll
            for (int kk = 0; kk < 2; kk++)
                ap[kk] = *(const bf16x8*)&Ps[wave][rb][lrow*64 + (((kk*4 + lquad) ^ (lrow & 7)) * 8)];
            #pragma unroll
            for (int kk = 0; kk < 2; kk++) {
                #pragma unroll
                for (int ct = 0; ct < 4; ct++)
                    oacc[rb][ct] = __builtin_amdgcn_mfma_f32_16x16x32_bf16(ap[kk], bv[ct][kk], oacc[rb][ct], 0, 0, 0);
                oacc[rb][4] = __builtin_amdgcn_mfma_f32_16x16x32_bf16(ap[kk], bv4[kk], oacc[rb][4], 0, 0, 0);
            }
        }

        if (kt + 1 < NSEQ / 64) {
            #pragma unroll
            for (int rr = 0; rr < 4; rr++) {
                *(bf16x8*)&Ks[1-p][(r2 + rr*16)*64 + ccs] = kr[rr];
                *(bf16x8*)&Vs[1-p][(r2 + rr*16)*64 + ccs] = vr[rr];
            }
        }
        __syncthreads();
    }

    #pragma unroll
    for (int rb = 0; rb < 4; rb++)
        #pragma unroll
        for (int r = 0; r < 4; r++) {
            const float inv = __builtin_amdgcn_rcpf(oacc[rb][4][r]);
            const int n = q0 + rb*16 + lquad*4 + r;
            #pragma unroll
            for (int ct = 0; ct < 4; ct++) {
                const int col = h*DH + ct*16 + lrow;
                ob[((size_t)b * NSEQ + n) * DIM + col] = f2bf(oacc[rb][ct][r] * inv);
            }
        }
}

// ---------------------------------------------------------------------------
// Kernel 3: out projection, operand-swapped -> float4 stores. grid (64, 6).
// ---------------------------------------------------------------------------
__global__ __launch_bounds__(256, 4) void out_proj_kernel(
    const short* __restrict__ xo, const short* __restrict__ W,
    const float* __restrict__ bias, float* __restrict__ y)
{
    __shared__ __align__(16) short As[2][128*32];
    __shared__ __align__(16) short Bs[2][128*32];

    const int wave = threadIdx.x >> 6, lane = threadIdx.x & 63;
    const int lr = lane & 15, lq = lane >> 4;
    const int m0 = blockIdx.x * 128;
    const int o0 = blockIdx.y * 128;

    const short* __restrict__ gA = xo + (size_t)(m0 + wave*32 + (lane>>2)) * DIM + (lane&3)*8;
    const short* __restrict__ gB = W  + (size_t)(o0 + wave*32 + (lane>>2)) * DIM + (lane&3)*8;

    const int wm = (wave & 1) * 64, wn = (wave >> 1) * 64;

    f32x4 acc[4][4];
    #pragma unroll
    for (int i = 0; i < 4; i++)
        #pragma unroll
        for (int j = 0; j < 4; j++) acc[i][j] = (f32x4){0.f, 0.f, 0.f, 0.f};

    GLL(gA,            &As[0][(wave*32     )*32]);
    GLL(gA + 16*DIM,   &As[0][(wave*32 + 16)*32]);
    GLL(gB,            &Bs[0][(wave*32     )*32]);
    GLL(gB + 16*DIM,   &Bs[0][(wave*32 + 16)*32]);
    __syncthreads();

    for (int kt = 0; kt < 24; kt++) {
        const int p = kt & 1;
        if (kt < 23) {
            const int k1 = (kt + 1) * 32;
            GLL(gA + k1,          &As[1-p][(wave*32     )*32]);
            GLL(gA + k1 + 16*DIM, &As[1-p][(wave*32 + 16)*32]);
            GLL(gB + k1,          &Bs[1-p][(wave*32     )*32]);
            GLL(gB + k1 + 16*DIM, &Bs[1-p][(wave*32 + 16)*32]);
        }
        bf16x8 a[4], b[4];
        #pragma unroll
        for (int i = 0; i < 4; i++)
            a[i] = *(const bf16x8*)&As[p][(wm + i*16 + lr)*32 + lq*8];
        #pragma unroll
        for (int j = 0; j < 4; j++)
            b[j] = *(const bf16x8*)&Bs[p][(wn + j*16 + lr)*32 + lq*8];
        #pragma unroll
        for (int i = 0; i < 4; i++)
            #pragma unroll
            for (int j = 0; j < 4; j++)
                acc[i][j] = __builtin_amdgcn_mfma_f32_16x16x32_bf16(b[j], a[i], acc[i][j], 0, 0, 0);
        __syncthreads();
    }

    // swapped: C row(reg) = o (4 consecutive), col(lane) = m -> float4 stores
    #pragma unroll
    for (int j = 0; j < 4; j++) {
        const int o = o0 + wn + j*16 + lq*4;
        const float4 bv = *(const float4*)&bias[o];
        #pragma unroll
        for (int i = 0; i < 4; i++) {
            const int m = m0 + wm + i*16 + lr;
            float4 v;
            v.x = acc[i][j][0] + bv.x;
            v.y = acc[i][j][1] + bv.y;
            v.z = acc[i][j][2] + bv.z;
            v.w = acc[i][j][3] + bv.w;
            *(float4*)&y[(size_t)m * DIM + o] = v;
        }
    }
}

extern "C" void kernel_launch(void* const* d_in, const int* in_sizes, int n_in,
                              void* d_out, int out_size, void* d_ws, size_t ws_size,
                              hipStream_t stream) {
    const float* x  = (const float*)d_in[0];
    const float* wq = (const float*)d_in[1];
    const float* wk = (const float*)d_in[2];
    const float* wv = (const float*)d_in[3];
    const float* wo = (const float*)d_in[4];
    const float* bo = (const float*)d_in[5];
    float* out = (float*)d_out;

    const size_t qkv_elems = (size_t)BATCH * HEADS * NSEQ * DH;  // 6291456
    short* xb  = (short*)d_ws;
    short* wqb = xb  + NX;
    short* wkb = wqb + NW;
    short* wvb = wkb + NW;
    short* wob = wvb + NW;
    short* qb  = wob + NW;
    short* kb  = qb  + qkv_elems;
    short* vtb = kb  + qkv_elems;
    short* ob  = xb;                    // alias: xb dead after qkv_proj

    convert_kernel <<<dim3((NX + 4*NW) / 1024), dim3(256), 0, stream>>>(x, wq, wk, wv, wo,
                                                                        xb, wqb, wkb, wvb, wob);
    qkv_proj_kernel<<<dim3(64, 18), dim3(256), 0, stream>>>(xb, wqb, wkb, wvb, qb, kb, vtb);
    attn_kernel    <<<dim3(768), dim3(128), 0, stream>>>(qb, kb, vtb, ob);
    out_proj_kernel<<<dim3(64, 6), dim3(256), 0, stream>>>(ob, wob, bo, out);
}

// Round 10
// 438.737 us; speedup vs baseline: 1.1137x; 1.1137x over previous
//
#include <hip/hip_runtime.h>
#include <hip/hip_bf16.h>

// MSA: x[2,4096,768] f32, wq/wk/wv/wo[768,768] f32, bo[768] f32 -> out f32
// (0) fp32->bf16 convert, (1) fused QKV GEMM (GLL staging, dbuf; epilogue
// LDS-transpose -> fully coalesced b128 stores; Q pre-scaled by 0.125*log2e),
// (2) flash attention (4 waves x 32 q-rows, swizzled LDS dbuf K/V, raw
// v_exp_f32 + v_perm pack, l-sum via ones-column MFMA), (3) out proj GEMM
// (LDS-transpose fp32 epilogue, bias folded).

#define HEADS 12
#define NSEQ  4096
#define DIM   768
#define DH    64
#define BATCH 2
#define QSCALE 0.18033688f   // (1/8) * log2(e)

typedef __attribute__((ext_vector_type(8))) short bf16x8;
typedef __attribute__((ext_vector_type(4))) float f32x4;
typedef __attribute__((ext_vector_type(4))) short bf16x4;

static __device__ __forceinline__ short f2bf(float f) {
    __hip_bfloat16 h = __float2bfloat16(f);
    return *reinterpret_cast<short*>(&h);
}

// RNE round two fp32 -> packed bf16x2
static __device__ __forceinline__ unsigned pkbf(float a, float b) {
    unsigned ua = __float_as_uint(a), ub = __float_as_uint(b);
    ua += 0x7FFFu + ((ua >> 16) & 1u);
    ub += 0x7FFFu + ((ub >> 16) & 1u);
    return __builtin_amdgcn_perm(ub, ua, 0x07060302);
}

// async global->LDS, 16B per lane
#define GLL(g, l) __builtin_amdgcn_global_load_lds( \
    (const __attribute__((address_space(1))) void*)(g), \
    (__attribute__((address_space(3))) void*)(l), 16, 0, 0)

#define NX (BATCH*NSEQ*DIM)   // 6291456
#define NW (DIM*DIM)          // 589824

// ---------------------------------------------------------------------------
// Kernel 0: fp32 -> bf16 convert.
// ---------------------------------------------------------------------------
__global__ __launch_bounds__(256) void convert_kernel(
    const float* __restrict__ x,  const float* __restrict__ wq,
    const float* __restrict__ wk, const float* __restrict__ wv,
    const float* __restrict__ wo,
    short* __restrict__ xb, short* __restrict__ wqb, short* __restrict__ wkb,
    short* __restrict__ wvb, short* __restrict__ wob)
{
    int i = (blockIdx.x * 256 + threadIdx.x) * 4;
    const float* src; short* dst; int off;
    if      (i < NX)          { src = x;  dst = xb;  off = i; }
    else if (i < NX + NW)     { src = wq; dst = wqb; off = i - NX; }
    else if (i < NX + 2*NW)   { src = wk; dst = wkb; off = i - NX - NW; }
    else if (i < NX + 3*NW)   { src = wv; dst = wvb; off = i - NX - 2*NW; }
    else                      { src = wo; dst = wob; off = i - NX - 3*NW; }
    float4 f = *(const float4*)(src + off);
    bf16x4 o; o[0] = f2bf(f.x); o[1] = f2bf(f.y); o[2] = f2bf(f.z); o[3] = f2bf(f.w);
    *(bf16x4*)(dst + off) = o;
}

// ---------------------------------------------------------------------------
// Kernel 1: fused QKV GEMM. 128x128 block (4 waves, 64x64 quadrants).
// BK=32, GLL staging, dbuf, 1 barrier/step. grid (64, 18).
// Q/K: swapped mfma(b,a) -> C reg=dd, lane=n. V: normal -> C reg=n, lane=dd.
// Epilogue: acc -> swizzled LDS tile (reusing As/Bs) -> coalesced b128 stores.
// ---------------------------------------------------------------------------
__global__ __launch_bounds__(256, 4) void qkv_proj_kernel(
    const short* __restrict__ xb, const short* __restrict__ wqb,
    const short* __restrict__ wkb, const short* __restrict__ wvb,
    short* __restrict__ qb, short* __restrict__ kb, short* __restrict__ vtb)
{
    __shared__ __align__(16) short Smem[16384];   // As[2]|Bs[2] in K-loop; 128x128 tile in epilogue

    const int wave = threadIdx.x >> 6, lane = threadIdx.x & 63;
    const int lr = lane & 15, lq = lane >> 4;
    const int which = blockIdx.y / 6;
    const short* __restrict__ W = (which == 0) ? wqb : ((which == 1) ? wkb : wvb);
    const int m0  = blockIdx.x * 128;
    const int o0l = (blockIdx.y % 6) * 128;

    const short* __restrict__ gA = xb + (size_t)(m0  + wave*32 + (lane>>2)) * DIM + (lane&3)*8;
    const short* __restrict__ gB = W  + (size_t)(o0l + wave*32 + (lane>>2)) * DIM + (lane&3)*8;

    const int wm = (wave & 1) * 64, wn = (wave >> 1) * 64;

    f32x4 acc[4][4];
    #pragma unroll
    for (int i = 0; i < 4; i++)
        #pragma unroll
        for (int j = 0; j < 4; j++) acc[i][j] = (f32x4){0.f, 0.f, 0.f, 0.f};

    GLL(gA,            &Smem[       (wave*32     )*32]);
    GLL(gA + 16*DIM,   &Smem[       (wave*32 + 16)*32]);
    GLL(gB,            &Smem[8192 + (wave*32     )*32]);
    GLL(gB + 16*DIM,   &Smem[8192 + (wave*32 + 16)*32]);
    __syncthreads();

    for (int kt = 0; kt < 24; kt++) {
        const int p = kt & 1;
        if (kt < 23) {
            const int k1 = (kt + 1) * 32;
            GLL(gA + k1,          &Smem[       (1-p)*4096 + (wave*32     )*32]);
            GLL(gA + k1 + 16*DIM, &Smem[       (1-p)*4096 + (wave*32 + 16)*32]);
            GLL(gB + k1,          &Smem[8192 + (1-p)*4096 + (wave*32     )*32]);
            GLL(gB + k1 + 16*DIM, &Smem[8192 + (1-p)*4096 + (wave*32 + 16)*32]);
        }
        bf16x8 a[4], b[4];
        #pragma unroll
        for (int i = 0; i < 4; i++)
            a[i] = *(const bf16x8*)&Smem[       p*4096 + (wm + i*16 + lr)*32 + lq*8];
        #pragma unroll
        for (int j = 0; j < 4; j++)
            b[j] = *(const bf16x8*)&Smem[8192 + p*4096 + (wn + j*16 + lr)*32 + lq*8];
        if (which == 2) {
            #pragma unroll
            for (int i = 0; i < 4; i++)
                #pragma unroll
                for (int j = 0; j < 4; j++)
                    acc[i][j] = __builtin_amdgcn_mfma_f32_16x16x32_bf16(a[i], b[j], acc[i][j], 0, 0, 0);
        } else {
            #pragma unroll
            for (int i = 0; i < 4; i++)
                #pragma unroll
                for (int j = 0; j < 4; j++)
                    acc[i][j] = __builtin_amdgcn_mfma_f32_16x16x32_bf16(b[j], a[i], acc[i][j], 0, 0, 0);
        }
        __syncthreads();
    }
    // K-loop done; all waves past final barrier -> Smem reusable as 128x128 tile.

    if (which == 2) {
        // C[m=n reg][o=dd lane]. LDS tile T[dd_local][n_local], chunk-swizzled.
        #pragma unroll
        for (int i = 0; i < 4; i++)
            #pragma unroll
            for (int j = 0; j < 4; j++) {
                const int row = wn + j*16 + lr;          // dd_local
                const int col = wm + i*16 + lq*4;        // n_local base
                const unsigned lo = pkbf(acc[i][j][0], acc[i][j][1]);
                const unsigned hi = pkbf(acc[i][j][2], acc[i][j][3]);
                const int ch = col >> 3, sub = col & 7;
                *(uint2*)&Smem[row*128 + ((ch ^ (row & 15)) * 8) + sub] = (uint2){lo, hi};
            }
        __syncthreads();
        const int bb = m0 >> 12, nn0 = m0 & (NSEQ - 1);
        #pragma unroll
        for (int it = 0; it < 8; it++) {
            const int c = threadIdx.x + it*256;          // 0..2047
            const int row = c >> 4, ch = c & 15;         // dd_local, n-chunk
            bf16x8 v = *(bf16x8*)&Smem[row*128 + ((ch ^ (row & 15)) * 8)];
            const int o = o0l + row;
            const int h = o >> 6, dd = o & 63;
            *(bf16x8*)(vtb + ((size_t)(bb*HEADS + h) * DH + dd) * NSEQ + nn0 + ch*8) = v;
        }
    } else {
        // swapped C[o=dd reg][m=n lane]. LDS tile T[n_local][o_local], chunk-swizzled.
        const float scale = (which == 0) ? QSCALE : 1.0f;
        #pragma unroll
        for (int i = 0; i < 4; i++)
            #pragma unroll
            for (int j = 0; j < 4; j++) {
                const int row = wm + i*16 + lr;          // n_local
                const int col = wn + j*16 + lq*4;        // o_local base
                const unsigned lo = pkbf(acc[i][j][0]*scale, acc[i][j][1]*scale);
                const unsigned hi = pkbf(acc[i][j][2]*scale, acc[i][j][3]*scale);
                const int ch = col >> 3, sub = col & 7;
                *(uint2*)&Smem[row*128 + ((ch ^ (row & 15)) * 8) + sub] = (uint2){lo, hi};
            }
        __syncthreads();
        short* __restrict__ dst = (which == 0) ? qb : kb;
        #pragma unroll
        for (int it = 0; it < 8; it++) {
            const int c = threadIdx.x + it*256;
            const int row = c >> 4, ch = c & 15;         // n_local, o-chunk
            bf16x8 v = *(bf16x8*)&Smem[row*128 + ((ch ^ (row & 15)) * 8)];
            const int m = m0 + row;
            const int bb = m >> 12, nn = m & (NSEQ - 1);
            const int o = o0l + ch*8;
            const int h = o >> 6, dd = o & 63;
            *(bf16x8*)(dst + (((size_t)(bb*HEADS + h) * NSEQ) + nn) * DH + dd) = v;
        }
    }
}

// ---------------------------------------------------------------------------
// Kernel 2: flash attention (round-8 structure). 768 blocks (XCD swizzle),
// 4 waves x 32 q-rows. Swizzled LDS, dbuf K/V, 1 barrier/tile. S^T = K Q^T;
// raw v_exp_f32 + v_perm pack; PV + hoisted ones-column for l.
// ---------------------------------------------------------------------------
__global__ __launch_bounds__(256, 3) void attn_kernel(
    const short* __restrict__ qb, const short* __restrict__ kb,
    const short* __restrict__ vtb, short* __restrict__ ob)
{
    __shared__ __align__(16) short Ks[2][64*64];
    __shared__ __align__(16) short Vs[2][64*64];
    __shared__ __align__(16) short Vones[16*64];
    __shared__ __align__(16) short Ps[4][2][16*64];

    const int wave = threadIdx.x >> 6, lane = threadIdx.x & 63;
    const int lrow = lane & 15, lquad = lane >> 4;

    const int flat = blockIdx.x;
    const int xcd  = flat & 7;
    const int idx  = flat >> 3;
    const int bh   = xcd * 3 + (idx % 3);
    const int qblk = idx / 3;
    const int b = bh / HEADS, h = bh % HEADS;
    const int q0 = qblk * 128 + wave * 32;

    const short* __restrict__ Q  = qb  + (size_t)bh * NSEQ * DH;
    const short* __restrict__ K  = kb  + (size_t)bh * NSEQ * DH;
    const short* __restrict__ Vt = vtb + (size_t)bh * DH * NSEQ;

    for (int i = threadIdx.x; i < 16*64; i += 256) Vones[i] = 0x3F80;

    const int t  = threadIdx.x;
    const int r2 = t >> 3, cc = t & 7;
    const int ccs = (cc ^ (r2 & 7)) * 8;

    bf16x8 aq[2][2];
    #pragma unroll
    for (int rb = 0; rb < 2; rb++)
        #pragma unroll
        for (int kk = 0; kk < 2; kk++)
            aq[rb][kk] = *(const bf16x8*)(Q + (size_t)(q0 + rb*16 + lrow) * DH + kk*32 + lquad*8);

    f32x4 oacc[2][5];
    #pragma unroll
    for (int rb = 0; rb < 2; rb++)
        #pragma unroll
        for (int ct = 0; ct < 5; ct++) oacc[rb][ct] = (f32x4){0.f, 0.f, 0.f, 0.f};

    {
        bf16x8 k0a = *(const bf16x8*)(K  + (size_t)(r2     ) * DH   + cc*8);
        bf16x8 k0b = *(const bf16x8*)(K  + (size_t)(r2 + 32) * DH   + cc*8);
        bf16x8 v0a = *(const bf16x8*)(Vt + (size_t)(r2     ) * NSEQ + cc*8);
        bf16x8 v0b = *(const bf16x8*)(Vt + (size_t)(r2 + 32) * NSEQ + cc*8);
        *(bf16x8*)&Ks[0][ r2     *64 + ccs] = k0a;
        *(bf16x8*)&Ks[0][(r2+32) *64 + ccs] = k0b;
        *(bf16x8*)&Vs[0][ r2     *64 + ccs] = v0a;
        *(bf16x8*)&Vs[0][(r2+32) *64 + ccs] = v0b;
    }
    __syncthreads();

    bf16x8 bv4[2];
    #pragma unroll
    for (int kk = 0; kk < 2; kk++)
        bv4[kk] = *(const bf16x8*)&Vones[lrow*64 + (((kk*4 + lquad) ^ (lrow & 7)) * 8)];

    for (int kt = 0; kt < NSEQ / 64; kt++) {
        const int p = kt & 1;
        bf16x8 kr0, kr1, vr0, vr1;
        if (kt + 1 < NSEQ / 64) {
            const int key1 = (kt + 1) * 64;
            kr0 = *(const bf16x8*)(K  + (size_t)(key1 + r2     ) * DH   + cc*8);
            kr1 = *(const bf16x8*)(K  + (size_t)(key1 + r2 + 32) * DH   + cc*8);
            vr0 = *(const bf16x8*)(Vt + (size_t)(r2     ) * NSEQ + key1 + cc*8);
            vr1 = *(const bf16x8*)(Vt + (size_t)(r2 + 32) * NSEQ + key1 + cc*8);
        }

        bf16x8 ak[4][2];
        #pragma unroll
        for (int ct = 0; ct < 4; ct++)
            #pragma unroll
            for (int kk = 0; kk < 2; kk++)
                ak[ct][kk] = *(const bf16x8*)&Ks[p][(ct*16 + lrow)*64 + (((kk*4 + lquad) ^ (lrow & 7)) * 8)];

        #pragma unroll
        for (int rb = 0; rb < 2; rb++) {
            f32x4 s[4];
            #pragma unroll
            for (int ct = 0; ct < 4; ct++) s[ct] = (f32x4){0.f, 0.f, 0.f, 0.f};
            #pragma unroll
            for (int kk = 0; kk < 2; kk++)
                #pragma unroll
                for (int ct = 0; ct < 4; ct++)
                    s[ct] = __builtin_amdgcn_mfma_f32_16x16x32_bf16(ak[ct][kk], aq[rb][kk], s[ct], 0, 0, 0);
            #pragma unroll
            for (int ct = 0; ct < 4; ct++) {
                const float e0 = __builtin_amdgcn_exp2f(s[ct][0]);
                const float e1 = __builtin_amdgcn_exp2f(s[ct][1]);
                const float e2 = __builtin_amdgcn_exp2f(s[ct][2]);
                const float e3 = __builtin_amdgcn_exp2f(s[ct][3]);
                const unsigned lo = pkbf(e0, e1), hi = pkbf(e2, e3);
                const int cps = (((ct*2 + (lquad >> 1)) ^ (lrow & 7)) * 8) + (lquad & 1) * 4;
                *(uint2*)&Ps[wave][rb][lrow*64 + cps] = (uint2){lo, hi};
            }
        }

        bf16x8 bv[4][2];
        #pragma unroll
        for (int ct = 0; ct < 4; ct++)
            #pragma unroll
            for (int kk = 0; kk < 2; kk++)
                bv[ct][kk] = *(const bf16x8*)&Vs[p][(ct*16 + lrow)*64 + (((kk*4 + lquad) ^ (lrow & 7)) * 8)];

        #pragma unroll
        for (int rb = 0; rb < 2; rb++) {
            bf16x8 ap[2];
            #pragma unroll
            for (int kk = 0; kk < 2; kk++)
                ap[kk] = *(const bf16x8*)&Ps[wave][rb][lrow*64 + (((kk*4 + lquad) ^ (lrow & 7)) * 8)];
            #pragma unroll
            for (int kk = 0; kk < 2; kk++) {
                #pragma unroll
                for (int ct = 0; ct < 4; ct++)
                    oacc[rb][ct] = __builtin_amdgcn_mfma_f32_16x16x32_bf16(ap[kk], bv[ct][kk], oacc[rb][ct], 0, 0, 0);
                oacc[rb][4] = __builtin_amdgcn_mfma_f32_16x16x32_bf16(ap[kk], bv4[kk], oacc[rb][4], 0, 0, 0);
            }
        }

        if (kt + 1 < NSEQ / 64) {
            *(bf16x8*)&Ks[1-p][ r2     *64 + ccs] = kr0;
            *(bf16x8*)&Ks[1-p][(r2+32) *64 + ccs] = kr1;
            *(bf16x8*)&Vs[1-p][ r2     *64 + ccs] = vr0;
            *(bf16x8*)&Vs[1-p][(r2+32) *64 + ccs] = vr1;
        }
        __syncthreads();
    }

    #pragma unroll
    for (int rb = 0; rb < 2; rb++)
        #pragma unroll
        for (int r = 0; r < 4; r++) {
            const float inv = __builtin_amdgcn_rcpf(oacc[rb][4][r]);
            const int n = q0 + rb*16 + lquad*4 + r;
            #pragma unroll
            for (int ct = 0; ct < 4; ct++) {
                const int col = h*DH + ct*16 + lrow;
                ob[((size_t)b * NSEQ + n) * DIM + col] = f2bf(oacc[rb][ct][r] * inv);
            }
        }
}

// ---------------------------------------------------------------------------
// Kernel 3: out projection (swapped math), LDS-transpose fp32 epilogue in
// 2 half-tile passes, bias folded. grid (64, 6).
// ---------------------------------------------------------------------------
__global__ __launch_bounds__(256, 4) void out_proj_kernel(
    const short* __restrict__ xo, const short* __restrict__ W,
    const float* __restrict__ bias, float* __restrict__ y)
{
    __shared__ __align__(16) short Smem[16384];   // K-loop: As|Bs; epilogue: 64x128 fp32

    const int wave = threadIdx.x >> 6, lane = threadIdx.x & 63;
    const int lr = lane & 15, lq = lane >> 4;
    const int m0 = blockIdx.x * 128;
    const int o0 = blockIdx.y * 128;

    const short* __restrict__ gA = xo + (size_t)(m0 + wave*32 + (lane>>2)) * DIM + (lane&3)*8;
    const short* __restrict__ gB = W  + (size_t)(o0 + wave*32 + (lane>>2)) * DIM + (lane&3)*8;

    const int wm = (wave & 1) * 64, wn = (wave >> 1) * 64;

    f32x4 acc[4][4];
    #pragma unroll
    for (int i = 0; i < 4; i++)
        #pragma unroll
        for (int j = 0; j < 4; j++) acc[i][j] = (f32x4){0.f, 0.f, 0.f, 0.f};

    GLL(gA,            &Smem[       (wave*32     )*32]);
    GLL(gA + 16*DIM,   &Smem[       (wave*32 + 16)*32]);
    GLL(gB,            &Smem[8192 + (wave*32     )*32]);
    GLL(gB + 16*DIM,   &Smem[8192 + (wave*32 + 16)*32]);
    __syncthreads();

    for (int kt = 0; kt < 24; kt++) {
        const int p = kt & 1;
        if (kt < 23) {
            const int k1 = (kt + 1) * 32;
            GLL(gA + k1,          &Smem[       (1-p)*4096 + (wave*32     )*32]);
            GLL(gA + k1 + 16*DIM, &Smem[       (1-p)*4096 + (wave*32 + 16)*32]);
            GLL(gB + k1,          &Smem[8192 + (1-p)*4096 + (wave*32     )*32]);
            GLL(gB + k1 + 16*DIM, &Smem[8192 + (1-p)*4096 + (wave*32 + 16)*32]);
        }
        bf16x8 a[4], b[4];
        #pragma unroll
        for (int i = 0; i < 4; i++)
            a[i] = *(const bf16x8*)&Smem[       p*4096 + (wm + i*16 + lr)*32 + lq*8];
        #pragma unroll
        for (int j = 0; j < 4; j++)
            b[j] = *(const bf16x8*)&Smem[8192 + p*4096 + (wn + j*16 + lr)*32 + lq*8];
        #pragma unroll
        for (int i = 0; i < 4; i++)
            #pragma unroll
            for (int j = 0; j < 4; j++)
                acc[i][j] = __builtin_amdgcn_mfma_f32_16x16x32_bf16(b[j], a[i], acc[i][j], 0, 0, 0);
        __syncthreads();
    }

    // swapped C: reg quad = 4 consecutive o, lane = m. Two passes of 64 rows.
    float* T32 = (float*)Smem;   // [64][128]
    for (int pass = 0; pass < 2; pass++) {
        #pragma unroll
        for (int ii = 0; ii < 2; ii++) {
            const int i = pass*2 + ii;
            const int r32 = (wm >> 1) + ii*16 + lr;      // 0..63 LDS row
            #pragma unroll
            for (int j = 0; j < 4; j++) {
                const int o_l = wn + j*16 + lq*4;
                const float4 bv = *(const float4*)&bias[o0 + o_l];
                float4 v;
                v.x = acc[i][j][0] + bv.x;
                v.y = acc[i][j][1] + bv.y;
                v.z = acc[i][j][2] + bv.z;
                v.w = acc[i][j][3] + bv.w;
                const int ch = o_l >> 2;                 // float4 chunk 0..31
                *(float4*)&T32[r32*128 + ((ch ^ (r32 & 7)) << 2)] = v;
            }
        }
        __syncthreads();
        #pragma unroll
        for (int it = 0; it < 8; it++) {
            const int c = threadIdx.x + it*256;          // 0..2047
            const int r32 = c >> 5, ch = c & 31;
            float4 v = *(float4*)&T32[r32*128 + ((ch ^ (r32 & 7)) << 2)];
            const int m = m0 + (r32 >> 5)*64 + pass*32 + (r32 & 31);
            *(float4*)&y[(size_t)m * DIM + o0 + ch*4] = v;
        }
        __syncthreads();
    }
}

extern "C" void kernel_launch(void* const* d_in, const int* in_sizes, int n_in,
                              void* d_out, int out_size, void* d_ws, size_t ws_size,
                              hipStream_t stream) {
    const float* x  = (const float*)d_in[0];
    const float* wq = (const float*)d_in[1];
    const float* wk = (const float*)d_in[2];
    const float* wv = (const float*)d_in[3];
    const float* wo = (const float*)d_in[4];
    const float* bo = (const float*)d_in[5];
    float* out = (float*)d_out;

    const size_t qkv_elems = (size_t)BATCH * HEADS * NSEQ * DH;  // 6291456
    short* xb  = (short*)d_ws;
    short* wqb = xb  + NX;
    short* wkb = wqb + NW;
    short* wvb = wkb + NW;
    short* wob = wvb + NW;
    short* qb  = wob + NW;
    short* kb  = qb  + qkv_elems;
    short* vtb = kb  + qkv_elems;
    short* ob  = xb;                    // alias: xb dead after qkv_proj

    convert_kernel <<<dim3((NX + 4*NW) / 1024), dim3(256), 0, stream>>>(x, wq, wk, wv, wo,
                                                                        xb, wqb, wkb, wvb, wob);
    qkv_proj_kernel<<<dim3(64, 18), dim3(256), 0, stream>>>(xb, wqb, wkb, wvb, qb, kb, vtb);
    attn_kernel    <<<dim3(768), dim3(256), 0, stream>>>(qb, kb, vtb, ob);
    out_proj_kernel<<<dim3(64, 6), dim3(256), 0, stream>>>(ob, wob, bo, out);
}